// Round 7
// baseline (94.128 us; speedup 1.0000x reference)
//
#include <hip/hip_runtime.h>

// LightweightConv1d: x (T,B,C) f32, weight (H,1,K) f32 (softmax over K), bias (C) f32
// out[t,b,c] = bias[c] + sum_k softmax(w[h])[k] * x[t-P+k, b, c],  h = c / (C/H)
//
// Streaming multi-accumulator + BATCHED loads. R6 (VGPR=36) showed the compiler
// kept 1 load in flight -> latency-bound at 50% VALU. Here the 62-input stream
// is issued in batches of 16 with an asm ordering fence (all 16 results must be
// register-resident before any FMA) -> 16-deep MLP per wave; per-batch compute
// (~992 cyc) covers the ~500 cyc cache latency. 32 acc + 16 batch + addr < 128
// VGPR budget (launch_bounds(256,4)) -> no spill (R5) and no remat (R3/R4).
#define T_DIM 2048
#define B_DIM 32
#define C_DIM 512
#define H_DIM 16
#define K_DIM 31
#define P_PAD 15
#define TT 32                      // outputs (accumulators) per thread
#define JN (TT + K_DIM - 1)        // 62 streamed inputs per thread
#define BATCH 16                   // loads in flight per batch
#define NCOL (B_DIM * C_DIM)       // 16384 floats between consecutive t

__global__ __launch_bounds__(256, 4)
void lwconv_kernel(const float* __restrict__ x, const float* __restrict__ weight,
                   const float* __restrict__ bias, float* __restrict__ out)
{
    const int wid  = __builtin_amdgcn_readfirstlane((int)(threadIdx.x >> 6));
    const int lane = threadIdx.x & 63;
    const int gw   = blockIdx.x * 4 + wid;        // global wave id (scalar)
    const int h    = gw & (H_DIM - 1);            // head (wave-uniform)
    const int bp   = (gw >> 4) & 15;              // batch pair (uniform)
    const int tblk = gw >> 8;                     // t-block 0..63 (uniform)
    const int c    = (h << 5) | (lane & 31);      // 32 channels of head h
    const int b    = (bp << 1) | (lane >> 5);     // 2 batches per wave
    const int col  = b * C_DIM + c;               // two 128B segments per wave

    // per-lane softmax of the head's 31 weights (uniform inputs), then -> SGPR
    float w[K_DIM];
    float m = -3.4e38f;
    #pragma unroll
    for (int k = 0; k < K_DIM; ++k) { w[k] = weight[h * K_DIM + k]; m = fmaxf(m, w[k]); }
    float s = 0.f;
    #pragma unroll
    for (int k = 0; k < K_DIM; ++k) { w[k] = __expf(w[k] - m); s += w[k]; }
    const float inv = 1.f / s;
    unsigned int ws[K_DIM];
    #pragma unroll
    for (int k = 0; k < K_DIM; ++k)
        ws[k] = __builtin_amdgcn_readfirstlane(__float_as_uint(w[k] * inv));

    const float bv = bias[c];
    const int tb = tblk * TT;                     // first output t of this thread
    const float* xp = x + col;
    float*       op = out + col;

    float acc[TT];
    #pragma unroll
    for (int i = 0; i < TT; ++i) acc[i] = bv;

    // Stream 62 inputs in 16-deep batches: {issue 16 loads} -> fence -> {FMAs}.
    #pragma unroll
    for (int jb = 0; jb < JN; jb += BATCH) {
        const int bn = (JN - jb) < BATCH ? (JN - jb) : BATCH;  // 16,16,16,14
        float v[BATCH];
        #pragma unroll
        for (int u = 0; u < BATCH; ++u) {
            if (u < bn) {
                const int t  = tb - P_PAD + (jb + u);          // block-uniform
                int tc = t < 0 ? 0 : (t >= T_DIM ? T_DIM - 1 : t);
                float vv = xp[(size_t)tc * NCOL];
                if (t < 0 || t >= T_DIM) vv = 0.f;             // uniform cndmask
                v[u] = vv;
            } else {
                v[u] = 0.f;
            }
        }
        // Ordering fence: all BATCH load results must be in VGPRs here.
        // Loads can't sink below it; FMAs can't hoist above it.
        asm volatile("" : "+v"(v[0]), "+v"(v[1]), "+v"(v[2]),  "+v"(v[3]),
                          "+v"(v[4]), "+v"(v[5]), "+v"(v[6]),  "+v"(v[7]),
                          "+v"(v[8]), "+v"(v[9]), "+v"(v[10]), "+v"(v[11]),
                          "+v"(v[12]),"+v"(v[13]),"+v"(v[14]), "+v"(v[15]));
        #pragma unroll
        for (int u = 0; u < BATCH; ++u) {
            if (u < bn) {
                const int j   = jb + u;
                const int ilo = (j - (K_DIM - 1)) > 0 ? (j - (K_DIM - 1)) : 0;
                const int ihi = j < (TT - 1) ? j : (TT - 1);
                #pragma unroll
                for (int i = ilo; i <= ihi; ++i)
                    acc[i] = fmaf(__uint_as_float(ws[j - i]), v[u], acc[i]);
            }
        }
    }

    #pragma unroll
    for (int i = 0; i < TT; ++i)
        op[(size_t)(tb + i) * NCOL] = acc[i];
}

extern "C" void kernel_launch(void* const* d_in, const int* in_sizes, int n_in,
                              void* d_out, int out_size, void* d_ws, size_t ws_size,
                              hipStream_t stream) {
    const float* x      = (const float*)d_in[0];
    const float* weight = (const float*)d_in[1];
    const float* bias   = (const float*)d_in[2];
    float* out = (float*)d_out;
    // waves = H(16) * batch-pairs(16) * t-blocks(64) = 16384 -> 4096 blocks of 4 waves.
    dim3 grid(H_DIM * 16 * (T_DIM / TT) / 4);
    dim3 block(256);
    lwconv_kernel<<<grid, block, 0, stream>>>(x, weight, bias, out);
}